// Round 4
// baseline (413.246 us; speedup 1.0000x reference)
//
#include <hip/hip_runtime.h>
#include <hip/hip_bf16.h>
#include <stdint.h>

#define NTOK 49
#define NP   64
#define DIMC 128
#define NHEAD 4
#define HD   32
#define SCALE 0.17677669529663687f
#define NEGBIG -30000.0f

typedef __bf16 bf16;
typedef __bf16 bf16x8 __attribute__((ext_vector_type(8)));
typedef __bf16 bf16x4 __attribute__((ext_vector_type(4)));
typedef float  f32x4  __attribute__((ext_vector_type(4)));

// LDS element offsets (bf16 elems). Total 32768 elems = 65536 B.
#define XO_S 136        // x rows (token x 128feat), stride 136 (16B-aligned rows)
#define QK_S 32
#define VT_S 72
#define P_S  72
#define Q_OFF  0        // q overlays x region (x dead after A-frags loaded + barrier)
#define K_OFF  8704
#define VT_OFF 16896
#define P_OFF  26112
#define OT_OFF 30720
#define SM_ELEMS 32768

// Compiler-only ordering fence for same-wave LDS RAW across differently-typed
// vector accesses (TBAA hazard). HW DS pipe is per-wave in-order.
#define LDS_FENCE() asm volatile("" ::: "memory")

__device__ __forceinline__ f32x4 mfma16(bf16x8 a, bf16x8 b, f32x4 c) {
  return __builtin_amdgcn_mfma_f32_16x16x32_bf16(a, b, c, 0, 0, 0);
}

// Sanitize: insurance against wrong-dtype garbage -> finite wrong (diagnosable),
// never NaN. No-op for genuine fp32 activations.
__device__ __forceinline__ float sanf(float v) {
  return (__builtin_fabsf(v) < 1e10f) ? v : 0.0f;
}
__device__ __forceinline__ bf16 b16s(float v) { return (bf16)sanf(v); }

// Load 8 consecutive floats, convert to bf16x8 (MFMA fragment).
__device__ __forceinline__ bf16x8 ldw8(const float* __restrict__ p) {
  f32x4 a = *(const f32x4*)p;
  f32x4 c = *(const f32x4*)(p + 4);
  bf16x8 r;
#pragma unroll
  for (int j = 0; j < 4; ++j) { r[j] = b16s(a[j]); r[4 + j] = b16s(c[j]); }
  return r;
}

__global__ __launch_bounds__(256, 2)
void winattn(const float* __restrict__ xg, const float* __restrict__ maskg,
             const float* __restrict__ qkvw, const float* __restrict__ qkvb,
             const float* __restrict__ rpb, const float* __restrict__ projw,
             const float* __restrict__ projb, const int* __restrict__ rel,
             float* __restrict__ out) {
  __shared__ bf16 sm[SM_ELEMS];

  const int b    = blockIdx.x;
  const int tid  = threadIdx.x;
  const int w    = tid >> 6;        // wave id 0..3
  const int lane = tid & 63;
  const int ln15 = lane & 15;
  const int quad = lane >> 4;

  // ---------- phase -1: zero-init ALL of LDS (pad rows + read-before-write
  // insurance: residual reads yield 0.0, never junk) ----------
  {
    bf16x8 z = (bf16x8)(bf16)0.0f;
#pragma unroll
    for (int it = 0; it < 16; ++it)
      *(bf16x8*)&sm[(tid + it * 256) * 8] = z;
  }
  __syncthreads();

  // ---------- phase 0: stage x (49x128 fp32 -> bf16) into LDS ----------
  {
    const float* xb = xg + (size_t)b * (NTOK * DIMC);
#pragma unroll
    for (int it = 0; it < 4; ++it) {
      int i = tid + it * 256;
      if (i < 784) {                       // 784 = 49*128/8
        int row = i >> 4;
        int col = (i & 15) << 3;
        *(bf16x8*)&sm[row * XO_S + col] = ldw8(&xb[i * 8]);
      }
    }
  }

  // ---------- gather attention bias (mask + rel-pos-bias) into registers ----------
  // This lane's query column nq; it holds S^T elements m = mt*16 + quad*4 + r.
  const int nq = w * 16 + ln15;
  float  maskv[16];
  bf16x4 rpbv[16];
  {
    const int bwin = b & 63;
    const int n_c = (nq < NTOK) ? nq : (NTOK - 1);
    int relv[16];
#pragma unroll
    for (int e = 0; e < 16; ++e) {
      int m   = (e >> 2) * 16 + quad * 4 + (e & 3);
      int m_c = (m < NTOK) ? m : (NTOK - 1);
      int rv  = rel[n_c * NTOK + m_c];
      relv[e] = ((unsigned)rv <= 168u) ? rv : 0;   // clamp: OOB-gather insurance
    }
#pragma unroll
    for (int e = 0; e < 16; ++e) {
      f32x4 t = *(const f32x4*)&rpb[relv[e] * 4];  // all 4 heads at once
      bf16x4 r;
#pragma unroll
      for (int j = 0; j < 4; ++j) r[j] = b16s(t[j]);
      rpbv[e] = r;
    }
#pragma unroll
    for (int e = 0; e < 16; ++e) {
      int m = (e >> 2) * 16 + quad * 4 + (e & 3);
      bool valid = (m < NTOK) && (nq < NTOK);
      maskv[e] = valid ? sanf(maskg[((size_t)bwin * NTOK + nq) * NTOK + m])
                       : NEGBIG;
    }
  }

  __syncthreads();   // x staged

  // ---------- phase 1a: load all A-fragments of x (then x region is dead) ----------
  bf16x8 afrag[4][4];
#pragma unroll
  for (int mt = 0; mt < 4; ++mt)
#pragma unroll
    for (int ks = 0; ks < 4; ++ks)
      afrag[mt][ks] = *(const bf16x8*)&sm[(mt * 16 + ln15) * XO_S + ks * 32 + quad * 8];

  __syncthreads();   // everyone finished reading x; q may overlay it now

  // ---------- phase 1b: QKV projection, wave w computes head w ----------
#pragma unroll
  for (int s = 0; s < 3; ++s) {
#pragma unroll
    for (int t = 0; t < 2; ++t) {
      const int j0 = s * DIMC + w * HD + t * 16;
      bf16x8 bfrag[4];
#pragma unroll
      for (int ks = 0; ks < 4; ++ks)
        bfrag[ks] = ldw8(&qkvw[(size_t)(j0 + ln15) * DIMC + ks * 32 + quad * 8]);
      const float bias = sanf(qkvb[j0 + ln15]);
      f32x4 acc[4];
#pragma unroll
      for (int mt = 0; mt < 4; ++mt) {
        acc[mt] = (f32x4)(0.0f);
#pragma unroll
        for (int ks = 0; ks < 4; ++ks)
          acc[mt] = mfma16(afrag[mt][ks], bfrag[ks], acc[mt]);
      }
      if (s == 0) {            // q: (acc+bias)*SCALE, layout [h][token][d]
#pragma unroll
        for (int mt = 0; mt < 4; ++mt)
#pragma unroll
          for (int r = 0; r < 4; ++r) {
            int token = mt * 16 + quad * 4 + r;
            sm[Q_OFF + (w * NP + token) * QK_S + t * 16 + ln15] =
                (bf16)((acc[mt][r] + bias) * SCALE);
          }
      } else if (s == 1) {     // k: layout [h][token][d]
#pragma unroll
        for (int mt = 0; mt < 4; ++mt)
#pragma unroll
          for (int r = 0; r < 4; ++r) {
            int token = mt * 16 + quad * 4 + r;
            sm[K_OFF + (w * NP + token) * QK_S + t * 16 + ln15] =
                (bf16)(acc[mt][r] + bias);
          }
      } else {                 // v: transposed [h][d][m], packed 4-token writes
#pragma unroll
        for (int mt = 0; mt < 4; ++mt) {
          bf16x4 pk;
#pragma unroll
          for (int r = 0; r < 4; ++r) pk[r] = (bf16)(acc[mt][r] + bias);
          *(bf16x4*)&sm[VT_OFF + (w * HD + t * 16 + ln15) * VT_S + mt * 16 + quad * 4] = pk;
        }
      }
    }
  }

  __syncthreads();   // q,k,vT visible to all waves

  // ---------- phase 2: attention; wave w owns query columns [16w,16w+16) ----------
  f32x4 yacc[8];
#pragma unroll
  for (int jt = 0; jt < 8; ++jt) yacc[jt] = (f32x4)(0.0f);

#pragma unroll
  for (int h = 0; h < NHEAD; ++h) {
    // S^T = k * q  (M=m keys, N=n queries, K=d)
    bf16x8 bq = *(const bf16x8*)&sm[Q_OFF + (h * NP + nq) * QK_S + quad * 8];
    f32x4 st[4];
#pragma unroll
    for (int mt = 0; mt < 4; ++mt) {
      bf16x8 ak = *(const bf16x8*)&sm[K_OFF + (h * NP + mt * 16 + ln15) * QK_S + quad * 8];
      st[mt] = mfma16(ak, bq, (f32x4)(0.0f));
    }
    // add bias+mask, softmax over m (in-lane 16 values + quad butterfly)
    float mx = -3e38f;
#pragma unroll
    for (int mt = 0; mt < 4; ++mt)
#pragma unroll
      for (int r = 0; r < 4; ++r) {
        float v = st[mt][r] + maskv[mt * 4 + r] + (float)rpbv[mt * 4 + r][h];
        st[mt][r] = v;
        mx = fmaxf(mx, v);
      }
    mx = fmaxf(mx, __shfl_xor(mx, 16));
    mx = fmaxf(mx, __shfl_xor(mx, 32));
    float ssum = 0.0f;
#pragma unroll
    for (int mt = 0; mt < 4; ++mt)
#pragma unroll
      for (int r = 0; r < 4; ++r) {
        float p = __expf(st[mt][r] - mx);
        st[mt][r] = p;
        ssum += p;
      }
    ssum += __shfl_xor(ssum, 16);
    ssum += __shfl_xor(ssum, 32);
    const float inv = 1.0f / ssum;
    // P row-major [n][m], packed 4-m writes (rows disjoint per wave)
#pragma unroll
    for (int mt = 0; mt < 4; ++mt) {
      bf16x4 pk;
#pragma unroll
      for (int r = 0; r < 4; ++r) pk[r] = (bf16)(st[mt][r] * inv);
      *(bf16x4*)&sm[P_OFF + nq * P_S + mt * 16 + quad * 4] = pk;
    }
    LDS_FENCE();   // keep P writes ordered before P reads (TBAA hazard)
    // O^T = vT * P^T  (M=d, K=m, N=n-strip)
    f32x4 oa[2];
    oa[0] = (f32x4)(0.0f); oa[1] = (f32x4)(0.0f);
#pragma unroll
    for (int ks = 0; ks < 2; ++ks) {
      bf16x8 bp = *(const bf16x8*)&sm[P_OFF + nq * P_S + ks * 32 + quad * 8];
#pragma unroll
      for (int dt = 0; dt < 2; ++dt) {
        bf16x8 av = *(const bf16x8*)&sm[VT_OFF + (h * HD + dt * 16 + ln15) * VT_S + ks * 32 + quad * 8];
        oa[dt] = mfma16(av, bp, oa[dt]);
      }
    }
    // O tile -> per-wave LDS scratch [16 n][32 d] (packed 4-d writes)
#pragma unroll
    for (int dt = 0; dt < 2; ++dt) {
      bf16x4 ok;
#pragma unroll
      for (int r = 0; r < 4; ++r) ok[r] = (bf16)oa[dt][r];
      *(bf16x4*)&sm[OT_OFF + w * 512 + ln15 * 32 + dt * 16 + quad * 4] = ok;
    }
    LDS_FENCE();   // keep O writes ordered before O reads (TBAA hazard)
    // Y^T += projW(:, h-chunk) * O^T   (M=j 128, K=d 32, N=n-strip)
    bf16x8 bo = *(const bf16x8*)&sm[OT_OFF + w * 512 + ln15 * 32 + quad * 8];
#pragma unroll
    for (int jt = 0; jt < 8; ++jt) {
      bf16x8 aw = ldw8(&projw[(size_t)(jt * 16 + ln15) * DIMC + h * HD + quad * 8]);
      yacc[jt] = mfma16(aw, bo, yacc[jt]);
    }
    LDS_FENCE();   // keep this h's O reads ordered before next h's P/O writes
  }

  // ---------- phase 3: bias + store (fp32 output, 16B f32x4 stores) ----------
  if (nq < NTOK) {
    float* ob = out + (size_t)b * (NTOK * DIMC) + nq * DIMC;
#pragma unroll
    for (int jt = 0; jt < 8; ++jt) {
      f32x4 pbv = *(const f32x4*)&projb[jt * 16 + quad * 4];
      f32x4 y;
#pragma unroll
      for (int r = 0; r < 4; ++r) y[r] = yacc[jt][r] + sanf(pbv[r]);
      *(f32x4*)&ob[jt * 16 + quad * 4] = y;
    }
  }
}

extern "C" void kernel_launch(void* const* d_in, const int* in_sizes, int n_in,
                              void* d_out, int out_size, void* d_ws, size_t ws_size,
                              hipStream_t stream) {
  const float* x     = (const float*)d_in[0];
  const float* mask  = (const float*)d_in[1];
  const float* qkv_w = (const float*)d_in[2];
  const float* qkv_b = (const float*)d_in[3];
  const float* rpb   = (const float*)d_in[4];
  const float* prj_w = (const float*)d_in[5];
  const float* prj_b = (const float*)d_in[6];
  const int*   rel   = (const int*)d_in[7];
  float* out = (float*)d_out;
  const int B = in_sizes[0] / (NTOK * DIMC);   // 4096
  winattn<<<B, 256, 0, stream>>>(x, mask, qkv_w, qkv_b, rpb, prj_w, prj_b, rel, out);
}

// Round 5
// 353.648 us; speedup vs baseline: 1.1685x; 1.1685x over previous
//
#include <hip/hip_runtime.h>
#include <hip/hip_bf16.h>
#include <stdint.h>

#define NTOK 49
#define DIMC 128
#define NHEAD 4
#define SCALE 0.17677669529663687f

typedef __bf16 bf16;
typedef __bf16 bf16x8 __attribute__((ext_vector_type(8)));
typedef __bf16 bf16x4 __attribute__((ext_vector_type(4)));
typedef float  f32x4  __attribute__((ext_vector_type(4)));

// ---- LDS layout (bf16 elems), total 27136 elems = 54272 B -> 3 blocks/CU ----
// Q: rows [h*64+tok] stride 36 (72B: 18 words, gcd(18,32)=2 -> 2-way free)
// K: same, at K_OFF
// VT: rows [h*32+d] stride 68 (136B: 34 words, gcd=2 -> 2-way free)
// P  (overlays dead Q): rows [n] stride 72
// OT (overlays dead Q): rows [n] stride 36
#define QK_S 36
#define VT_S 68
#define P_S  72
#define OT_S 36
#define K_OFF  9216
#define VT_OFF 18432
#define P_OFF  0
#define OT_OFF 4608
#define SM_ELEMS 27136

// d_ws layout (bytes): comb bf16 [64][64][4][64] @0 (2 MB);
// qkvw bf16 @2097152 (98304 B); projw bf16 @2195456 (32768 B)
#define WS_QKVW_OFF 2097152
#define WS_PROJW_OFF 2195456

// Compiler-only ordering fence for same-wave LDS RAW (TBAA hazard insurance).
#define LDS_FENCE() asm volatile("" ::: "memory")

__device__ __forceinline__ f32x4 mfma16(bf16x8 a, bf16x8 b, f32x4 c) {
  return __builtin_amdgcn_mfma_f32_16x16x32_bf16(a, b, c, 0, 0, 0);
}
__device__ __forceinline__ bf16x8 cat8(bf16x4 lo, bf16x4 hi) {
  bf16x8 r;
#pragma unroll
  for (int j = 0; j < 4; ++j) { r[j] = lo[j]; r[4 + j] = hi[j]; }
  return r;
}
// 8B-aligned LDS fragment read as 2x b64 (row strides are 8B- but not 16B-
// aligned, so b128 is not provable -> conflict-free b64 pairs instead).
__device__ __forceinline__ bf16x8 ld8(const bf16* p) {
  return cat8(*(const bf16x4*)p, *(const bf16x4*)(p + 4));
}
// 8 consecutive fp32 -> bf16x8
__device__ __forceinline__ bf16x8 cvt8(const float* __restrict__ p) {
  f32x4 a = *(const f32x4*)p;
  f32x4 c = *(const f32x4*)(p + 4);
  bf16x8 r;
#pragma unroll
  for (int j = 0; j < 4; ++j) { r[j] = (bf16)a[j]; r[4 + j] = (bf16)c[j]; }
  return r;
}

// ---------------- prologue: build comb table + bf16 weights in d_ws ----------
__global__ __launch_bounds__(256)
void prep(const float* __restrict__ maskg, const float* __restrict__ rpb,
          const int* __restrict__ rel, const float* __restrict__ qkvw,
          const float* __restrict__ projw, bf16* __restrict__ comb,
          bf16* __restrict__ qkvw_b, bf16* __restrict__ projw_b) {
  int id = blockIdx.x * 256 + threadIdx.x;
  if (id < 64 * 64 * 4 * 64) {
    // comb[win][n][h][m] = mask[win][n][m] + rpb[rel[n][m]][h], -30000 at pads
    int m = id & 63, h = (id >> 6) & 3, n = (id >> 8) & 63, win = id >> 14;
    float v = -30000.0f;
    if (n < NTOK && m < NTOK)
      v = maskg[((size_t)win * NTOK + n) * NTOK + m] + rpb[rel[n * NTOK + m] * 4 + h];
    comb[id] = (bf16)v;
  } else {
    int t = id - 64 * 64 * 4 * 64;          // 0..65535
    if (t < 384 * 128) qkvw_b[t] = (bf16)qkvw[t];
    else               projw_b[t - 384 * 128] = (bf16)projw[t - 384 * 128];
  }
}

// ---------------- main kernel: one window per block, 4 waves ----------------
__global__ __launch_bounds__(256, 3)
void winattn(const float* __restrict__ xg, const float* __restrict__ qkvb,
             const float* __restrict__ projb, const bf16* __restrict__ comb,
             const bf16* __restrict__ qkvw_b, const bf16* __restrict__ projw_b,
             float* __restrict__ out) {
  __shared__ bf16 sm[SM_ELEMS];

  const int b    = blockIdx.x;
  const int tid  = threadIdx.x;
  const int w    = tid >> 6;        // wave id == head owned in phase 1
  const int lane = tid & 63;
  const int ln15 = lane & 15;
  const int quad = lane >> 4;
  const int nq   = w * 16 + ln15;   // this lane's query column (phase 2)

  // ---- x fragments straight from global (L1-backed; rows>=49 clamped; the
  // clamped-garbage q/k/v pad rows are neutralized by comb=-30000 masking) ----
  const float* xb = xg + (size_t)b * (NTOK * DIMC);
  bf16x8 xf[4][4];
#pragma unroll
  for (int mt = 0; mt < 4; ++mt) {
    int tok = mt * 16 + ln15;
    const float* xr = xb + (tok < NTOK ? tok : (NTOK - 1)) * DIMC;
#pragma unroll
    for (int ks = 0; ks < 4; ++ks)
      xf[mt][ks] = cvt8(&xr[ks * 32 + quad * 8]);
  }

  // ---- phase 1: QKV projection for head w.
  // q,k computed as W·x^T (A=W rows direct from global bf16, B=x-frag):
  //   C[j][tok] -> lane holds 4 consecutive d for one token -> packed b64 write.
  // v computed as x·W^T (A=x-frag, B=same W-frag!): lane holds 4 consecutive
  //   tokens for one d -> packed b64 write into transposed vT[d][m].
#pragma unroll
  for (int s = 0; s < 3; ++s) {
#pragma unroll
    for (int t = 0; t < 2; ++t) {
      const int j0 = s * DIMC + w * 32 + t * 16;
      bf16x8 wf[4];
#pragma unroll
      for (int ks = 0; ks < 4; ++ks)
        wf[ks] = *(const bf16x8*)&qkvw_b[(size_t)(j0 + ln15) * DIMC + ks * 32 + quad * 8];
      if (s < 2) {
        f32x4 b4 = *(const f32x4*)&qkvb[j0 + quad * 4];
#pragma unroll
        for (int mt = 0; mt < 4; ++mt) {
          f32x4 acc = (f32x4)(0.0f);
#pragma unroll
          for (int ks = 0; ks < 4; ++ks)
            acc = mfma16(wf[ks], xf[mt][ks], acc);   // C[j=quad*4+r][tok=ln15]
          bf16x4 pk;
#pragma unroll
          for (int r = 0; r < 4; ++r) {
            float v = acc[r] + b4[r];
            pk[r] = (bf16)(s == 0 ? v * SCALE : v);
          }
          int row = w * 64 + mt * 16 + ln15;         // [h][token]
          bf16* dst = s == 0 ? &sm[row * QK_S + t * 16 + quad * 4]
                             : &sm[K_OFF + row * QK_S + t * 16 + quad * 4];
          *(bf16x4*)dst = pk;
        }
      } else {
        float bv = qkvb[j0 + ln15];
#pragma unroll
        for (int mt = 0; mt < 4; ++mt) {
          f32x4 acc = (f32x4)(0.0f);
#pragma unroll
          for (int ks = 0; ks < 4; ++ks)
            acc = mfma16(xf[mt][ks], wf[ks], acc);   // C[tok=quad*4+r][j=ln15]
          bf16x4 pk;
#pragma unroll
          for (int r = 0; r < 4; ++r) pk[r] = (bf16)(acc[r] + bv);
          *(bf16x4*)&sm[VT_OFF + (w * 32 + t * 16 + ln15) * VT_S + mt * 16 + quad * 4] = pk;
        }
      }
    }
  }

  __syncthreads();   // q,k,vT visible to all waves

  // ---- preload this wave's q fragments for all heads, then free Q region ----
  bf16x8 bql[NHEAD];
#pragma unroll
  for (int h = 0; h < NHEAD; ++h)
    bql[h] = ld8(&sm[(h * 64 + nq) * QK_S + quad * 8]);
  __syncthreads();   // Q dead; P/OT may overlay it

  // ---- phase 2: per-head attention; wave w owns query columns [16w,16w+16) ----
  const bf16* cbase = comb + ((size_t)(b & 63) * 64 + nq) * (4 * 64);
  f32x4 yacc[8];
#pragma unroll
  for (int jt = 0; jt < 8; ++jt) yacc[jt] = (f32x4)(0.0f);

#pragma unroll
  for (int h = 0; h < NHEAD; ++h) {
    // S^T = k·q^T : lane holds S^T[m=mt*16+quad*4+r][n=nq]
    f32x4 st[4];
#pragma unroll
    for (int mt = 0; mt < 4; ++mt) {
      bf16x8 ak = ld8(&sm[K_OFF + (h * 64 + mt * 16 + ln15) * QK_S + quad * 8]);
      st[mt] = mfma16(ak, bql[h], (f32x4)(0.0f));
    }
    // + combined bias (mask + rpb, pads = -30000), softmax over m
    const bf16* cb = cbase + h * 64;
    float mx = -3e38f;
#pragma unroll
    for (int mt = 0; mt < 4; ++mt) {
      bf16x4 cv = *(const bf16x4*)&cb[mt * 16 + quad * 4];
#pragma unroll
      for (int r = 0; r < 4; ++r) {
        float v = st[mt][r] + (float)cv[r];
        st[mt][r] = v;
        mx = fmaxf(mx, v);
      }
    }
    mx = fmaxf(mx, __shfl_xor(mx, 16));
    mx = fmaxf(mx, __shfl_xor(mx, 32));
    float ssum = 0.0f;
#pragma unroll
    for (int mt = 0; mt < 4; ++mt)
#pragma unroll
      for (int r = 0; r < 4; ++r) {
        float p = __expf(st[mt][r] - mx);
        st[mt][r] = p;
        ssum += p;
      }
    ssum += __shfl_xor(ssum, 16);
    ssum += __shfl_xor(ssum, 32);
    const float inv = 1.0f / ssum;
    // P[n][m] packed writes (wave-private rows)
#pragma unroll
    for (int mt = 0; mt < 4; ++mt) {
      bf16x4 pk;
#pragma unroll
      for (int r = 0; r < 4; ++r) pk[r] = (bf16)(st[mt][r] * inv);
      *(bf16x4*)&sm[P_OFF + nq * P_S + mt * 16 + quad * 4] = pk;
    }
    LDS_FENCE();
    // O^T = vT·P^T : lane holds O^T[d=dt*16+quad*4+r][n=nq]
    f32x4 oa[2];
    oa[0] = (f32x4)(0.0f); oa[1] = (f32x4)(0.0f);
#pragma unroll
    for (int ks = 0; ks < 2; ++ks) {
      bf16x8 bp = ld8(&sm[P_OFF + nq * P_S + ks * 32 + quad * 8]);
#pragma unroll
      for (int dt = 0; dt < 2; ++dt) {
        bf16x8 av = ld8(&sm[VT_OFF + (h * 32 + dt * 16 + ln15) * VT_S + ks * 32 + quad * 8]);
        oa[dt] = mfma16(av, bp, oa[dt]);
      }
    }
    // O -> wave-private OT[n][d] (packed), re-read as B-frag for proj
#pragma unroll
    for (int dt = 0; dt < 2; ++dt) {
      bf16x4 ok;
#pragma unroll
      for (int r = 0; r < 4; ++r) ok[r] = (bf16)oa[dt][r];
      *(bf16x4*)&sm[OT_OFF + nq * OT_S + dt * 16 + quad * 4] = ok;
    }
    LDS_FENCE();
    bf16x8 bo = ld8(&sm[OT_OFF + nq * OT_S + quad * 8]);
    // Y^T += projW(:,h·32..)·O^T  (A=projw rows direct from global bf16)
#pragma unroll
    for (int jt = 0; jt < 8; ++jt) {
      bf16x8 aw = *(const bf16x8*)&projw_b[(size_t)(jt * 16 + ln15) * DIMC + h * 32 + quad * 8];
      yacc[jt] = mfma16(aw, bo, yacc[jt]);
    }
    LDS_FENCE();
  }

  // ---- epilogue: + projb, fp32 16B stores; lane column = token nq ----
  if (nq < NTOK) {
    float* ob = out + (size_t)b * (NTOK * DIMC) + nq * DIMC;
#pragma unroll
    for (int jt = 0; jt < 8; ++jt) {
      f32x4 pbv = *(const f32x4*)&projb[jt * 16 + quad * 4];
      f32x4 y;
#pragma unroll
      for (int r = 0; r < 4; ++r) y[r] = yacc[jt][r] + pbv[r];
      *(f32x4*)&ob[jt * 16 + quad * 4] = y;
    }
  }
}

extern "C" void kernel_launch(void* const* d_in, const int* in_sizes, int n_in,
                              void* d_out, int out_size, void* d_ws, size_t ws_size,
                              hipStream_t stream) {
  const float* x     = (const float*)d_in[0];
  const float* mask  = (const float*)d_in[1];
  const float* qkv_w = (const float*)d_in[2];
  const float* qkv_b = (const float*)d_in[3];
  const float* rpb   = (const float*)d_in[4];
  const float* prj_w = (const float*)d_in[5];
  const float* prj_b = (const float*)d_in[6];
  const int*   rel   = (const int*)d_in[7];
  float* out = (float*)d_out;

  bf16* ws_comb  = (bf16*)d_ws;
  bf16* ws_qkvw  = (bf16*)((char*)d_ws + WS_QKVW_OFF);
  bf16* ws_projw = (bf16*)((char*)d_ws + WS_PROJW_OFF);

  const int B = in_sizes[0] / (NTOK * DIMC);   // 4096
  // prologue: 4096 blocks for comb (1M elems) + 256 for weight conversion
  prep<<<4352, 256, 0, stream>>>(mask, rpb, rel, qkv_w, prj_w,
                                 ws_comb, ws_qkvw, ws_projw);
  winattn<<<B, 256, 0, stream>>>(x, qkv_b, prj_b, ws_comb, ws_qkvw, ws_projw, out);
}

// Round 6
// 351.348 us; speedup vs baseline: 1.1762x; 1.0065x over previous
//
#include <hip/hip_runtime.h>
#include <hip/hip_bf16.h>
#include <stdint.h>

#define NTOK 49
#define DIMC 128
#define NHEAD 4
#define SCALE 0.17677669529663687f

typedef __bf16 bf16;
typedef __bf16 bf16x8 __attribute__((ext_vector_type(8)));
typedef __bf16 bf16x4 __attribute__((ext_vector_type(4)));
typedef float  f32x4  __attribute__((ext_vector_type(4)));

// ---- LDS layout (bf16 elems), total 27136 elems = 54272 B -> 3 blocks/CU ----
// Region0 [0,9216): phase1 Q rows [h*64+tok] stride 36 (18 words, 2-way free);
//   after bq preload it becomes 4 per-wave-private 2304-elem slots holding
//   P (rows [ln15] stride 72) then OT (rows [ln15] stride 132, 66 words).
// K  at 9216: rows [h*64+tok] stride 36
// VT at 18432: rows [h*32+d] stride 68 (34 words, 2-way free)
#define QK_S 36
#define VT_S 68
#define P_S  72
#define OT_S 132
#define WPRIV 2304
#define K_OFF  9216
#define VT_OFF 18432
#define SM_ELEMS 27136

// d_ws layout (bytes): comb bf16 [64][64][4][64] @0 (2 MB);
// qkvw bf16 @2097152 (98304 B); projw bf16 @2195456 (32768 B)
#define WS_QKVW_OFF 2097152
#define WS_PROJW_OFF 2195456

__device__ __forceinline__ f32x4 mfma16(bf16x8 a, bf16x8 b, f32x4 c) {
  return __builtin_amdgcn_mfma_f32_16x16x32_bf16(a, b, c, 0, 0, 0);
}
__device__ __forceinline__ bf16x8 cat8(bf16x4 lo, bf16x4 hi) {
  bf16x8 r;
#pragma unroll
  for (int j = 0; j < 4; ++j) { r[j] = lo[j]; r[4 + j] = hi[j]; }
  return r;
}
// 8B-aligned LDS fragment read as 2x b64. Same access type (bf16x4) as all
// LDS writes -> may-alias per C++ rules -> compiler preserves write->read
// order; HW DS pipe is per-wave in-order. No fences needed.
__device__ __forceinline__ bf16x8 ld8(const bf16* p) {
  return cat8(*(const bf16x4*)p, *(const bf16x4*)(p + 4));
}
__device__ __forceinline__ bf16x8 cvt8(const float* __restrict__ p) {
  f32x4 a = *(const f32x4*)p;
  f32x4 c = *(const f32x4*)(p + 4);
  bf16x8 r;
#pragma unroll
  for (int j = 0; j < 4; ++j) { r[j] = (bf16)a[j]; r[4 + j] = (bf16)c[j]; }
  return r;
}

// ---------------- prologue: build comb table + bf16 weights in d_ws ----------
__global__ __launch_bounds__(256)
void prep(const float* __restrict__ maskg, const float* __restrict__ rpb,
          const int* __restrict__ rel, const float* __restrict__ qkvw,
          const float* __restrict__ projw, bf16* __restrict__ comb,
          bf16* __restrict__ qkvw_b, bf16* __restrict__ projw_b) {
  int id = blockIdx.x * 256 + threadIdx.x;
  if (id < 64 * 64 * 4 * 64) {
    // comb[win][n][h][m] = mask[win][n][m] + rpb[rel[n][m]][h], -30000 at pads
    int m = id & 63, h = (id >> 6) & 3, n = (id >> 8) & 63, win = id >> 14;
    float v = -30000.0f;
    if (n < NTOK && m < NTOK)
      v = maskg[((size_t)win * NTOK + n) * NTOK + m] + rpb[rel[n * NTOK + m] * 4 + h];
    comb[id] = (bf16)v;
  } else {
    int t = id - 64 * 64 * 4 * 64;          // 0..65535
    if (t < 384 * 128) qkvw_b[t] = (bf16)qkvw[t];
    else               projw_b[t - 384 * 128] = (bf16)projw[t - 384 * 128];
  }
}

// ---------------- main kernel: one window per block, 4 waves ----------------
__global__ __launch_bounds__(256, 3)
void winattn(const float* __restrict__ xg, const float* __restrict__ qkvb,
             const float* __restrict__ projb, const bf16* __restrict__ comb,
             const bf16* __restrict__ qkvw_b, const bf16* __restrict__ projw_b,
             float* __restrict__ out) {
  __shared__ bf16 sm[SM_ELEMS];

  const int b    = blockIdx.x;
  const int tid  = threadIdx.x;
  const int w    = tid >> 6;        // wave id == head owned in phase 1
  const int lane = tid & 63;
  const int ln15 = lane & 15;
  const int quad = lane >> 4;
  const int nq   = w * 16 + ln15;   // this lane's query column (phase 2)

  // ---- x fragments straight from global (L1-backed; rows>=49 clamped; pad
  // rows are neutralized downstream by comb=-30000 and the output guard) ----
  const float* xb = xg + (size_t)b * (NTOK * DIMC);
  bf16x8 xf[4][4];
#pragma unroll
  for (int mt = 0; mt < 4; ++mt) {
    int tok = mt * 16 + ln15;
    const float* xr = xb + (tok < NTOK ? tok : (NTOK - 1)) * DIMC;
#pragma unroll
    for (int ks = 0; ks < 4; ++ks)
      xf[mt][ks] = cvt8(&xr[ks * 32 + quad * 8]);
  }

  // ---- phase 1: QKV projection for head w (q,k as W·x^T; v as x·W^T) ----
#pragma unroll
  for (int s = 0; s < 3; ++s) {
#pragma unroll
    for (int t = 0; t < 2; ++t) {
      const int j0 = s * DIMC + w * 32 + t * 16;
      bf16x8 wf[4];
#pragma unroll
      for (int ks = 0; ks < 4; ++ks)
        wf[ks] = *(const bf16x8*)&qkvw_b[(size_t)(j0 + ln15) * DIMC + ks * 32 + quad * 8];
      if (s < 2) {
        f32x4 b4 = *(const f32x4*)&qkvb[j0 + quad * 4];
#pragma unroll
        for (int mt = 0; mt < 4; ++mt) {
          f32x4 acc = (f32x4)(0.0f);
#pragma unroll
          for (int ks = 0; ks < 4; ++ks)
            acc = mfma16(wf[ks], xf[mt][ks], acc);   // C[j=quad*4+r][tok=ln15]
          bf16x4 pk;
#pragma unroll
          for (int r = 0; r < 4; ++r) {
            float v = acc[r] + b4[r];
            pk[r] = (bf16)(s == 0 ? v * SCALE : v);
          }
          int row = w * 64 + mt * 16 + ln15;         // [h][token]
          bf16* dst = s == 0 ? &sm[row * QK_S + t * 16 + quad * 4]
                             : &sm[K_OFF + row * QK_S + t * 16 + quad * 4];
          *(bf16x4*)dst = pk;
        }
      } else {
        float bv = qkvb[j0 + ln15];
#pragma unroll
        for (int mt = 0; mt < 4; ++mt) {
          f32x4 acc = (f32x4)(0.0f);
#pragma unroll
          for (int ks = 0; ks < 4; ++ks)
            acc = mfma16(xf[mt][ks], wf[ks], acc);   // C[tok=quad*4+r][j=ln15]
          bf16x4 pk;
#pragma unroll
          for (int r = 0; r < 4; ++r) pk[r] = (bf16)(acc[r] + bv);
          *(bf16x4*)&sm[VT_OFF + (w * 32 + t * 16 + ln15) * VT_S + mt * 16 + quad * 4] = pk;
        }
      }
    }
  }

  __syncthreads();   // q,k,vT visible to all waves

  // ---- preload this wave's q fragments for all heads, then free region0 ----
  bf16x8 bql[NHEAD];
#pragma unroll
  for (int h = 0; h < NHEAD; ++h)
    bql[h] = ld8(&sm[(h * 64 + nq) * QK_S + quad * 8]);
  __syncthreads();   // Q dead; per-wave-private P/OT slots may overlay it

  // ---- prefetch combined bias (mask+rpb) for all heads: 16x 8B loads ----
  const bf16* cbase = comb + ((size_t)(b & 63) * 64 + nq) * (4 * 64);
  bf16x4 combv[NHEAD][4];
#pragma unroll
  for (int h = 0; h < NHEAD; ++h)
#pragma unroll
    for (int mt = 0; mt < 4; ++mt)
      combv[h][mt] = *(const bf16x4*)&cbase[h * 64 + mt * 16 + quad * 4];

  bf16* wpriv = &sm[w * WPRIV];     // this wave's private P/OT scratch

  // ---- phase 2: per-head attention; O kept in fp32 registers ----
  f32x4 oall[NHEAD][2];
#pragma unroll
  for (int h = 0; h < NHEAD; ++h) {
    // S^T = k·q^T : lane holds S^T[m=mt*16+quad*4+r][n=nq]
    f32x4 st[4];
#pragma unroll
    for (int mt = 0; mt < 4; ++mt) {
      bf16x8 ak = ld8(&sm[K_OFF + (h * 64 + mt * 16 + ln15) * QK_S + quad * 8]);
      st[mt] = mfma16(ak, bql[h], (f32x4)(0.0f));
    }
    // exp(logit+bias) without max-sub (bounded; clamp 60; -30000 underflows->0)
    float ssum = 0.0f;
#pragma unroll
    for (int mt = 0; mt < 4; ++mt) {
#pragma unroll
      for (int r = 0; r < 4; ++r) {
        float v = fminf(st[mt][r] + (float)combv[h][mt][r], 60.0f);
        float p = __expf(v);
        st[mt][r] = p;
        ssum += p;
      }
    }
    // un-normalized P -> LDS (wave-private rows); sum reduction overlaps
#pragma unroll
    for (int mt = 0; mt < 4; ++mt) {
      bf16x4 pk;
#pragma unroll
      for (int r = 0; r < 4; ++r) pk[r] = (bf16)st[mt][r];
      *(bf16x4*)&wpriv[ln15 * P_S + mt * 16 + quad * 4] = pk;
    }
    ssum += __shfl_xor(ssum, 16);
    ssum += __shfl_xor(ssum, 32);
    // O^T = vT·P^T, then scale by 1/sum
    f32x4 oa0 = (f32x4)(0.0f), oa1 = (f32x4)(0.0f);
#pragma unroll
    for (int ks = 0; ks < 2; ++ks) {
      bf16x8 bp = ld8(&wpriv[ln15 * P_S + ks * 32 + quad * 8]);
      bf16x8 av0 = ld8(&sm[VT_OFF + (h * 32 + ln15) * VT_S + ks * 32 + quad * 8]);
      bf16x8 av1 = ld8(&sm[VT_OFF + (h * 32 + 16 + ln15) * VT_S + ks * 32 + quad * 8]);
      oa0 = mfma16(av0, bp, oa0);
      oa1 = mfma16(av1, bp, oa1);
    }
    const float inv = 1.0f / ssum;
#pragma unroll
    for (int r = 0; r < 4; ++r) { oall[h][0][r] = oa0[r] * inv; oall[h][1][r] = oa1[r] * inv; }
  }

  // ---- OT[n][d=128] to private LDS (P dead), one pass ----
#pragma unroll
  for (int h = 0; h < NHEAD; ++h)
#pragma unroll
    for (int dt = 0; dt < 2; ++dt) {
      bf16x4 ok;
#pragma unroll
      for (int r = 0; r < 4; ++r) ok[r] = (bf16)oall[h][dt][r];
      *(bf16x4*)&wpriv[ln15 * OT_S + h * 32 + dt * 16 + quad * 4] = ok;
    }

  // ---- proj GEMM: Y^T = projW·O^T, K=128 in one run (32 MFMA, loads free
  // to hoist — no fences, no barriers) ----
  bf16x8 bo[4];
#pragma unroll
  for (int ks = 0; ks < 4; ++ks)
    bo[ks] = ld8(&wpriv[ln15 * OT_S + ks * 32 + quad * 8]);
  f32x4 yacc[8];
#pragma unroll
  for (int jt = 0; jt < 8; ++jt) {
    yacc[jt] = (f32x4)(0.0f);
#pragma unroll
    for (int ks = 0; ks < 4; ++ks) {
      bf16x8 aw = *(const bf16x8*)&projw_b[(size_t)(jt * 16 + ln15) * DIMC + ks * 32 + quad * 8];
      yacc[jt] = mfma16(aw, bo[ks], yacc[jt]);
    }
  }

  // ---- epilogue: + projb, fp32 16B stores; lane column = token nq ----
  if (nq < NTOK) {
    float* ob = out + (size_t)b * (NTOK * DIMC) + nq * DIMC;
#pragma unroll
    for (int jt = 0; jt < 8; ++jt) {
      f32x4 pbv = *(const f32x4*)&projb[jt * 16 + quad * 4];
      f32x4 y;
#pragma unroll
      for (int r = 0; r < 4; ++r) y[r] = yacc[jt][r] + pbv[r];
      *(f32x4*)&ob[jt * 16 + quad * 4] = y;
    }
  }
}

extern "C" void kernel_launch(void* const* d_in, const int* in_sizes, int n_in,
                              void* d_out, int out_size, void* d_ws, size_t ws_size,
                              hipStream_t stream) {
  const float* x     = (const float*)d_in[0];
  const float* mask  = (const float*)d_in[1];
  const float* qkv_w = (const float*)d_in[2];
  const float* qkv_b = (const float*)d_in[3];
  const float* rpb   = (const float*)d_in[4];
  const float* prj_w = (const float*)d_in[5];
  const float* prj_b = (const float*)d_in[6];
  const int*   rel   = (const int*)d_in[7];
  float* out = (float*)d_out;

  bf16* ws_comb  = (bf16*)d_ws;
  bf16* ws_qkvw  = (bf16*)((char*)d_ws + WS_QKVW_OFF);
  bf16* ws_projw = (bf16*)((char*)d_ws + WS_PROJW_OFF);

  const int B = in_sizes[0] / (NTOK * DIMC);   // 4096
  prep<<<4352, 256, 0, stream>>>(mask, rpb, rel, qkv_w, prj_w,
                                 ws_comb, ws_qkvw, ws_projw);
  winattn<<<B, 256, 0, stream>>>(x, qkv_b, prj_b, ws_comb, ws_qkvw, ws_projw, out);
}